// Round 8
// baseline (234.183 us; speedup 1.0000x reference)
//
#include <hip/hip_runtime.h>
#include <hip/hip_bf16.h>
#include <math.h>

#define DI   2048      // D_INNER
#define DS   16        // D_STATE
#define DTR  128       // DT_RANK
#define NBATCH 2
#define SEQ  2048
#define ROWS (NBATCH*SEQ)   // 4096
#define NE   (DTR + 2*DS)   // 160
#define NC   64             // chunks along L
#define LC   (SEQ/NC)       // 32

typedef float f32x4 __attribute__((ext_vector_type(4)));
typedef short s16x8 __attribute__((ext_vector_type(8)));
typedef short s16x4 __attribute__((ext_vector_type(4)));

#define L2E 1.4426950408889634f

__device__ inline short f2bf(float f) {
    unsigned u = __builtin_bit_cast(unsigned, f);
    u += 0x7FFFu + ((u >> 16) & 1u);   // RNE
    return (short)(u >> 16);
}

// pack 2 floats -> 2 bf16 (RNE) in one u32 (lowers to v_cvt_pk_bf16_f32)
__device__ inline unsigned pk2(float lo, float hi) {
    union { __hip_bfloat162 h; unsigned u; } cv;
    cv.h = __float22bfloat162_rn(float2{lo, hi});
    return cv.u;
}

// ---------------- cast weights to bf16 ----------------
__global__ __launch_bounds__(256) void k_castw(const float* __restrict__ w,
                                               const float* __restrict__ dtw,
                                               short* __restrict__ wb,
                                               short* __restrict__ dtwb) {
    int i = blockIdx.x*256 + threadIdx.x;     // 4 elems each
    if (i < 81920) {                          // 160*2048/4
        float4 v = ((const float4*)w)[i];
        s16x4 o = { f2bf(v.x), f2bf(v.y), f2bf(v.z), f2bf(v.w) };
        *(s16x4*)(wb + 4*i) = o;
    } else if (i < 147456) {                  // + 2048*128/4
        int j = i - 81920;
        float4 v = ((const float4*)dtw)[j];
        s16x4 o = { f2bf(v.x), f2bf(v.y), f2bf(v.z), f2bf(v.w) };
        *(s16x4*)(dtwb + 4*j) = o;
    }
}

// ---------------- GEMM1: in-block K-split x4, LDS reduce, write dR/B/C directly ----------------
// 256 blocks x 512 thr = 2048 waves. wave = (half of 80 cols, K-quarter)
__global__ __launch_bounds__(512) void k_gemm1(const float* __restrict__ x,
                                               const short* __restrict__ wb,
                                               short* __restrict__ dRb,
                                               float* __restrict__ Bm,
                                               float* __restrict__ Cm) {
    __shared__ float lred[2][3][5][64][4];    // 30 KB
    const int tid  = threadIdx.x;
    const int w    = tid >> 6;                // 0..7
    const int lane = tid & 63;
    const int half = w & 1, kq = w >> 1;      // kq 0..3
    const int m16  = blockIdx.x;              // 0..255
    const int r = lane & 15, g = lane >> 4;

    f32x4 acc[5] = {};
    const float* xp    = x  + (size_t)(m16*16 + r)*DI + g*8 + kq*512;
    const short* wbase = wb + (size_t)(half*80 + r)*DI + g*8 + kq*512;
    #pragma unroll 4
    for (int kk = 0; kk < 16; ++kk) {
        const int k0 = kk*32;
        float4 xa = *(const float4*)(xp + k0);
        float4 xc = *(const float4*)(xp + k0 + 4);
        union { s16x8 v; unsigned u[4]; } af;
        af.u[0] = pk2(xa.x, xa.y);
        af.u[1] = pk2(xa.z, xa.w);
        af.u[2] = pk2(xc.x, xc.y);
        af.u[3] = pk2(xc.z, xc.w);
        #pragma unroll
        for (int nf = 0; nf < 5; ++nf) {
            s16x8 bfrag = *(const s16x8*)(wbase + (size_t)nf*16*DI + k0);
            acc[nf] = __builtin_amdgcn_mfma_f32_16x16x32_bf16(af.v, bfrag, acc[nf], 0, 0, 0);
        }
    }
    if (kq > 0) {
        #pragma unroll
        for (int nf = 0; nf < 5; ++nf)
            *(f32x4*)&lred[half][kq-1][nf][lane][0] = acc[nf];
    }
    __syncthreads();
    if (kq == 0) {
        #pragma unroll
        for (int nf = 0; nf < 5; ++nf)
            #pragma unroll
            for (int p = 0; p < 3; ++p)
                acc[nf] += *(const f32x4*)&lred[half][p][nf][lane][0];
        const int orow = m16*16 + g*4;
        #pragma unroll
        for (int nf = 0; nf < 5; ++nf) {
            const int gnf = half*5 + nf;
            const int col = gnf*16 + r;
            #pragma unroll
            for (int j = 0; j < 4; ++j) {
                const int row = orow + j;
                float v = acc[nf][j];
                if (gnf < 8)       dRb[(size_t)row*DTR + col]        = f2bf(v);
                else if (gnf == 8) Bm [(size_t)row*DS + (col - 128)] = v;
                else               Cm [(size_t)row*DS + (col - 144)] = v;
            }
        }
    }
}

// ---------------- GEMM2: delta(bf16) = softplus(dRb @ dtwb^T + bias) — no LDS ----------------
__global__ __launch_bounds__(256) void k_gemm2(const short* __restrict__ dRb,
                                               const short* __restrict__ dtwb,
                                               const float* __restrict__ bias,
                                               unsigned short* __restrict__ deltab) {
    const int wave = blockIdx.x*4 + (threadIdx.x >> 6);
    const int lane = threadIdx.x & 63;
    const int m16 = wave >> 5, nt = wave & 31;
    const int r = lane & 15, g = lane >> 4;

    s16x8 a[4];
    const short* ap = dRb + (size_t)(m16*16 + r)*DTR + g*8;
    #pragma unroll
    for (int ks = 0; ks < 4; ++ks) a[ks] = *(const s16x8*)(ap + ks*32);

    f32x4 acc[4] = {};
    #pragma unroll
    for (int nf = 0; nf < 4; ++nf) {
        const short* bp = dtwb + (size_t)(nt*64 + nf*16 + r)*DTR + g*8;
        #pragma unroll
        for (int ks = 0; ks < 4; ++ks) {
            s16x8 b = *(const s16x8*)(bp + ks*32);
            acc[nf] = __builtin_amdgcn_mfma_f32_16x16x32_bf16(a[ks], b, acc[nf], 0, 0, 0);
        }
    }
    const int orow = m16*16 + g*4;
    #pragma unroll
    for (int nf = 0; nf < 4; ++nf) {
        const int col = nt*64 + nf*16 + r;
        const float bb = bias[col];
        #pragma unroll
        for (int j = 0; j < 4; ++j) {
            float v = acc[nf][j] + bb;
            float sp = fmaxf(v, 0.f) + __logf(1.f + __expf(-fabsf(v)));
            deltab[(size_t)(orow + j)*DI + col] = (unsigned short)f2bf(sp);
        }
    }
}

// ---------------- scan pass 1: direct loads, DS-split x4, NC=64 ----------------
// 16384 waves. ap via exp2(An2 * sum(delta)); summaries [c][b][d][n]
__global__ __launch_bounds__(256) void k_scan1(const unsigned short* __restrict__ deltab,
                                               const float* __restrict__ x,
                                               const float* __restrict__ Bm,
                                               const float* __restrict__ A_log,
                                               float* __restrict__ aprod,
                                               float* __restrict__ rsum) {
    const int tid  = threadIdx.x;
    const int lane = tid & 63;
    const int w    = blockIdx.x*4 + (tid >> 6);   // 0..16383
    const int dlow = lane & 15, q = lane >> 4;
    const int d16  = w & 127;
    const int rest = w >> 7;                      // 0..127
    const int b = rest & 1, c = rest >> 1;        // c 0..63
    const int d = d16*16 + dlow;
    const int n0 = 4*q;

    float4 Alg = *(const float4*)(A_log + (size_t)d*DS + n0);
    float An2[4] = { -__expf(Alg.x)*L2E, -__expf(Alg.y)*L2E,
                     -__expf(Alg.z)*L2E, -__expf(Alg.w)*L2E };
    float r[4] = {0.f,0.f,0.f,0.f};
    float S = 0.f;

    const unsigned short* dp = deltab + (size_t)b*SEQ*DI + d;
    const float* xp = x  + (size_t)b*SEQ*DI + d;
    const float* bp = Bm + (size_t)b*SEQ*DS + n0;
    const int lbase = c*LC;
    #pragma unroll 4
    for (int tt = 0; tt < LC; ++tt) {
        const int l = lbase + tt;
        float dlt = __builtin_bit_cast(float, (unsigned)dp[(size_t)l*DI] << 16);
        float u   = xp[(size_t)l*DI];
        float du  = dlt * u;
        S += dlt;
        float4 bv = *(const float4*)(bp + (size_t)l*DS);
        float bbv[4] = {bv.x, bv.y, bv.z, bv.w};
        #pragma unroll
        for (int j = 0; j < 4; ++j) {
            float da = exp2f(An2[j] * dlt);
            r[j] = fmaf(da, r[j], du * bbv[j]);
        }
    }
    size_t base = (((size_t)c*NBATCH + b)*DI + d)*DS + n0;
    *(f32x4*)(aprod + base) = (f32x4){ exp2f(An2[0]*S), exp2f(An2[1]*S),
                                       exp2f(An2[2]*S), exp2f(An2[3]*S) };
    *(f32x4*)(rsum  + base) = (f32x4){ r[0], r[1], r[2], r[3] };
}

// ---------------- middle: sequential combine, hin written IN-PLACE over aprod ----------------
__global__ __launch_bounds__(256) void k_mid(float* ah,                       // aprod in, hin out
                                             const float* __restrict__ rsum) {
    int gid = blockIdx.x*256 + threadIdx.x;   // B*DI*DS = 65536
    int n = gid & 15;
    int d = (gid >> 4) & (DI-1);
    int b = gid >> 15;
    float h = 0.f;
    for (int c = 0; c < NC; c++) {
        size_t idx = (((size_t)c*NBATCH + b)*DI + d)*DS + n;
        float a  = ah[idx];
        float rr = rsum[idx];
        ah[idx] = h;                          // load-before-store in-place
        h = fmaf(a, h, rr);
    }
}

// ---------------- scan pass 2: direct loads, butterfly-reduce y ----------------
__global__ __launch_bounds__(256) void k_scan2(const unsigned short* __restrict__ deltab,
                                               const float* __restrict__ x,
                                               const float* __restrict__ Bm,
                                               const float* __restrict__ Cm,
                                               const float* __restrict__ A_log,
                                               const float* __restrict__ Dv,
                                               const float* __restrict__ hin,
                                               float* __restrict__ y) {
    const int tid  = threadIdx.x;
    const int lane = tid & 63;
    const int w    = blockIdx.x*4 + (tid >> 6);
    const int dlow = lane & 15, q = lane >> 4;
    const int d16  = w & 127;
    const int rest = w >> 7;
    const int b = rest & 1, c = rest >> 1;
    const int d = d16*16 + dlow;
    const int n0 = 4*q;

    float4 Alg = *(const float4*)(A_log + (size_t)d*DS + n0);
    float An2[4] = { -__expf(Alg.x)*L2E, -__expf(Alg.y)*L2E,
                     -__expf(Alg.z)*L2E, -__expf(Alg.w)*L2E };
    size_t base = (((size_t)c*NBATCH + b)*DI + d)*DS + n0;
    float4 hv = *(const float4*)(hin + base);
    float h[4] = {hv.x, hv.y, hv.z, hv.w};
    const float Dd = Dv[d];

    const unsigned short* dp = deltab + (size_t)b*SEQ*DI + d;
    const float* xp = x  + (size_t)b*SEQ*DI + d;
    const float* bp = Bm + (size_t)b*SEQ*DS + n0;
    const float* cp = Cm + (size_t)b*SEQ*DS + n0;
    float* yp = y + (size_t)b*SEQ*DI + d;
    const int lbase = c*LC;
    #pragma unroll 4
    for (int tt = 0; tt < LC; ++tt) {
        const int l = lbase + tt;
        float dlt = __builtin_bit_cast(float, (unsigned)dp[(size_t)l*DI] << 16);
        float u   = xp[(size_t)l*DI];
        float du  = dlt * u;
        float4 bv = *(const float4*)(bp + (size_t)l*DS);
        float4 cv = *(const float4*)(cp + (size_t)l*DS);
        float bbv[4] = {bv.x, bv.y, bv.z, bv.w};
        float ccv[4] = {cv.x, cv.y, cv.z, cv.w};
        float acc = 0.f;
        #pragma unroll
        for (int j = 0; j < 4; ++j) {
            float da = exp2f(An2[j] * dlt);
            h[j] = fmaf(da, h[j], du * bbv[j]);
            acc  = fmaf(h[j], ccv[j], acc);
        }
        acc += __shfl_xor(acc, 16);
        acc += __shfl_xor(acc, 32);
        if (q == 0) yp[(size_t)l*DI] = fmaf(u, Dd, acc);
    }
}

extern "C" void kernel_launch(void* const* d_in, const int* in_sizes, int n_in,
                              void* d_out, int out_size, void* d_ws, size_t ws_size,
                              hipStream_t stream) {
    const float* x     = (const float*)d_in[0];
    const float* A_log = (const float*)d_in[1];
    const float* Dv    = (const float*)d_in[2];
    const float* xpw   = (const float*)d_in[3];
    const float* dtw   = (const float*)d_in[4];
    const float* dtb   = (const float*)d_in[5];
    float* out = (float*)d_out;

    const size_t SCN = (size_t)NC*NBATCH*DS*DI;          // 4,194,304 floats

    float* ws    = (float*)d_ws;
    unsigned short* deltab = (unsigned short*)ws;        // ROWS*DI shorts
    float* aprod = ws + ((size_t)ROWS*DI/2);             // SCN floats (hin aliases after k_mid)
    float* rsum  = aprod + SCN;                          // SCN floats
    float* Bm    = rsum + SCN;                           // ROWS*DS
    float* Cm    = Bm + (size_t)ROWS*DS;                 // ROWS*DS
    short* dRb   = (short*)(Cm + (size_t)ROWS*DS);       // ROWS*DTR shorts
    short* wb    = dRb + (size_t)ROWS*DTR;               // 160*2048 shorts
    short* dtwb  = wb  + (size_t)160*2048;               // 2048*128 shorts

    k_castw<<<576, 256, 0, stream>>>(xpw, dtw, wb, dtwb);
    k_gemm1<<<256, 512, 0, stream>>>(x, wb, dRb, Bm, Cm);
    k_gemm2<<<2048, 256, 0, stream>>>(dRb, dtwb, dtb, deltab);
    k_scan1<<<4096, 256, 0, stream>>>(deltab, x, Bm, A_log, aprod, rsum);
    k_mid<<<256, 256, 0, stream>>>(aprod, rsum);
    k_scan2<<<4096, 256, 0, stream>>>(deltab, x, Bm, Cm, A_log, Dv, aprod, out);
}

// Round 9
// 230.284 us; speedup vs baseline: 1.0169x; 1.0169x over previous
//
#include <hip/hip_runtime.h>
#include <hip/hip_bf16.h>
#include <math.h>

#define DI   2048      // D_INNER
#define DS   16        // D_STATE
#define DTR  128       // DT_RANK
#define NBATCH 2
#define SEQ  2048
#define ROWS (NBATCH*SEQ)   // 4096
#define NE   (DTR + 2*DS)   // 160
#define NC   64             // chunks along L
#define LC   (SEQ/NC)       // 32

typedef float f32x4 __attribute__((ext_vector_type(4)));
typedef short s16x8 __attribute__((ext_vector_type(8)));
typedef short s16x4 __attribute__((ext_vector_type(4)));

#define L2E 1.4426950408889634f

__device__ inline short f2bf(float f) {
    unsigned u = __builtin_bit_cast(unsigned, f);
    u += 0x7FFFu + ((u >> 16) & 1u);   // RNE
    return (short)(u >> 16);
}

// pack 2 floats -> 2 bf16 (RNE) in one u32 (lowers to v_cvt_pk_bf16_f32)
__device__ inline unsigned pk2(float lo, float hi) {
    union { __hip_bfloat162 h; unsigned u; } cv;
    cv.h = __float22bfloat162_rn(float2{lo, hi});
    return cv.u;
}
// pack (delta_bf16 low | x_bf16 high)
__device__ inline unsigned packdu(short dbf, float xf) {
    return ((unsigned)(unsigned short)f2bf(xf) << 16) | (unsigned)(unsigned short)dbf;
}

// ---------------- cast weights to bf16 ----------------
__global__ __launch_bounds__(256) void k_castw(const float* __restrict__ w,
                                               const float* __restrict__ dtw,
                                               short* __restrict__ wb,
                                               short* __restrict__ dtwb) {
    int i = blockIdx.x*256 + threadIdx.x;     // 4 elems each
    if (i < 81920) {                          // 160*2048/4
        float4 v = ((const float4*)w)[i];
        s16x4 o = { f2bf(v.x), f2bf(v.y), f2bf(v.z), f2bf(v.w) };
        *(s16x4*)(wb + 4*i) = o;
    } else if (i < 147456) {                  // + 2048*128/4
        int j = i - 81920;
        float4 v = ((const float4*)dtw)[j];
        s16x4 o = { f2bf(v.x), f2bf(v.y), f2bf(v.z), f2bf(v.w) };
        *(s16x4*)(dtwb + 4*j) = o;
    }
}

// ---------------- GEMM1: in-block K-split x4, LDS reduce, write dR/B/C directly ----------------
__global__ __launch_bounds__(512) void k_gemm1(const float* __restrict__ x,
                                               const short* __restrict__ wb,
                                               short* __restrict__ dRb,
                                               float* __restrict__ Bm,
                                               float* __restrict__ Cm) {
    __shared__ float lred[2][3][5][64][4];    // 30 KB
    const int tid  = threadIdx.x;
    const int w    = tid >> 6;                // 0..7
    const int lane = tid & 63;
    const int half = w & 1, kq = w >> 1;      // kq 0..3
    const int m16  = blockIdx.x;              // 0..255
    const int r = lane & 15, g = lane >> 4;

    f32x4 acc[5] = {};
    const float* xp    = x  + (size_t)(m16*16 + r)*DI + g*8 + kq*512;
    const short* wbase = wb + (size_t)(half*80 + r)*DI + g*8 + kq*512;
    #pragma unroll 4
    for (int kk = 0; kk < 16; ++kk) {
        const int k0 = kk*32;
        float4 xa = *(const float4*)(xp + k0);
        float4 xc = *(const float4*)(xp + k0 + 4);
        union { s16x8 v; unsigned u[4]; } af;
        af.u[0] = pk2(xa.x, xa.y);
        af.u[1] = pk2(xa.z, xa.w);
        af.u[2] = pk2(xc.x, xc.y);
        af.u[3] = pk2(xc.z, xc.w);
        #pragma unroll
        for (int nf = 0; nf < 5; ++nf) {
            s16x8 bfrag = *(const s16x8*)(wbase + (size_t)nf*16*DI + k0);
            acc[nf] = __builtin_amdgcn_mfma_f32_16x16x32_bf16(af.v, bfrag, acc[nf], 0, 0, 0);
        }
    }
    if (kq > 0) {
        #pragma unroll
        for (int nf = 0; nf < 5; ++nf)
            *(f32x4*)&lred[half][kq-1][nf][lane][0] = acc[nf];
    }
    __syncthreads();
    if (kq == 0) {
        #pragma unroll
        for (int nf = 0; nf < 5; ++nf)
            #pragma unroll
            for (int p = 0; p < 3; ++p)
                acc[nf] += *(const f32x4*)&lred[half][p][nf][lane][0];
        const int orow = m16*16 + g*4;
        #pragma unroll
        for (int nf = 0; nf < 5; ++nf) {
            const int gnf = half*5 + nf;
            const int col = gnf*16 + r;
            #pragma unroll
            for (int j = 0; j < 4; ++j) {
                const int row = orow + j;
                float v = acc[nf][j];
                if (gnf < 8)       dRb[(size_t)row*DTR + col]        = f2bf(v);
                else if (gnf == 8) Bm [(size_t)row*DS + (col - 128)] = v;
                else               Cm [(size_t)row*DS + (col - 144)] = v;
            }
        }
    }
}

// ---------------- GEMM2: delta(bf16) = softplus(dRb @ dtwb^T + bias) — no LDS ----------------
__global__ __launch_bounds__(256) void k_gemm2(const short* __restrict__ dRb,
                                               const short* __restrict__ dtwb,
                                               const float* __restrict__ bias,
                                               unsigned short* __restrict__ deltab) {
    const int wave = blockIdx.x*4 + (threadIdx.x >> 6);
    const int lane = threadIdx.x & 63;
    const int m16 = wave >> 5, nt = wave & 31;
    const int r = lane & 15, g = lane >> 4;

    s16x8 a[4];
    const short* ap = dRb + (size_t)(m16*16 + r)*DTR + g*8;
    #pragma unroll
    for (int ks = 0; ks < 4; ++ks) a[ks] = *(const s16x8*)(ap + ks*32);

    f32x4 acc[4] = {};
    #pragma unroll
    for (int nf = 0; nf < 4; ++nf) {
        const short* bp = dtwb + (size_t)(nt*64 + nf*16 + r)*DTR + g*8;
        #pragma unroll
        for (int ks = 0; ks < 4; ++ks) {
            s16x8 b = *(const s16x8*)(bp + ks*32);
            acc[nf] = __builtin_amdgcn_mfma_f32_16x16x32_bf16(a[ks], b, acc[nf], 0, 0, 0);
        }
    }
    const int orow = m16*16 + g*4;
    #pragma unroll
    for (int nf = 0; nf < 4; ++nf) {
        const int col = nt*64 + nf*16 + r;
        const float bb = bias[col];
        #pragma unroll
        for (int j = 0; j < 4; ++j) {
            float v = acc[nf][j] + bb;
            float sp = fmaxf(v, 0.f) + __logf(1.f + __expf(-fabsf(v)));
            deltab[(size_t)(orow + j)*DI + col] = (unsigned short)f2bf(sp);
        }
    }
}

// ---------------- scan pass 1: LDS-staged (packed bf16 delta|x), NC=64 ----------------
__global__ __launch_bounds__(256) void k_scan1(const unsigned short* __restrict__ deltab,
                                               const float* __restrict__ x,
                                               const float* __restrict__ Bm,
                                               const float* __restrict__ A_log,
                                               float* __restrict__ aprod,
                                               float* __restrict__ rsum) {
    __shared__ unsigned lxd[LC][64];
    __shared__ float lB[LC][DS];
    const int tid = threadIdx.x;
    const int bb = blockIdx.x & 31;          // d-block 0..31
    const int b  = (blockIdx.x >> 5) & 1;
    const int c  = blockIdx.x >> 6;          // 0..63
    const int d0 = bb*64;
    const int lbase = c*LC;

    // ---- coalesced staging ----
    {
        const unsigned short* dsrc = deltab + ((size_t)(b*SEQ + lbase))*DI + d0;
        const float*          xsrc = x      + ((size_t)(b*SEQ + lbase))*DI + d0;
        const int row = tid >> 4, col = (tid & 15)*4;
        #pragma unroll
        for (int i = 0; i < 2; i++) {
            s16x4  dv = *(const s16x4*) (dsrc + (size_t)(row + 16*i)*DI + col);
            float4 xv = *(const float4*)(xsrc + (size_t)(row + 16*i)*DI + col);
            uint4 o;
            o.x = packdu(dv[0], xv.x);
            o.y = packdu(dv[1], xv.y);
            o.z = packdu(dv[2], xv.z);
            o.w = packdu(dv[3], xv.w);
            *(uint4*)&lxd[row + 16*i][col] = o;
        }
        if (tid < 128) {
            const float* bsrc = Bm + ((size_t)(b*SEQ + lbase))*DS;
            *(float4*)&lB[tid >> 2][(tid & 3)*4] = *(const float4*)(bsrc + tid*4);
        }
    }

    const int lane = tid & 63, widx = tid >> 6;
    const int dlow = lane & 15, q = lane >> 4;
    const int dcol = widx*16 + dlow;
    const int d = d0 + dcol;
    const int n0 = 4*q;

    float4 Alg = *(const float4*)(A_log + (size_t)d*DS + n0);
    float An2[4] = { -__expf(Alg.x)*L2E, -__expf(Alg.y)*L2E,
                     -__expf(Alg.z)*L2E, -__expf(Alg.w)*L2E };
    float r[4] = {0.f,0.f,0.f,0.f};
    float S = 0.f;

    __syncthreads();

    #pragma unroll 8
    for (int tt = 0; tt < LC; ++tt) {
        unsigned v = lxd[tt][dcol];
        float dlt = __builtin_bit_cast(float, v << 16);
        float u   = __builtin_bit_cast(float, v & 0xffff0000u);
        float du  = dlt * u;
        S += dlt;
        float4 bv = *(const float4*)&lB[tt][n0];
        float bbv[4] = {bv.x, bv.y, bv.z, bv.w};
        #pragma unroll
        for (int j = 0; j < 4; ++j) {
            float da = exp2f(An2[j] * dlt);
            r[j] = fmaf(da, r[j], du * bbv[j]);
        }
    }
    size_t base = (((size_t)c*NBATCH + b)*DI + d)*DS + n0;
    *(f32x4*)(aprod + base) = (f32x4){ exp2f(An2[0]*S), exp2f(An2[1]*S),
                                       exp2f(An2[2]*S), exp2f(An2[3]*S) };
    *(f32x4*)(rsum  + base) = (f32x4){ r[0], r[1], r[2], r[3] };
}

// ---------------- middle: 2-level combine, 8 threads/element, hin in-place ----------------
// summaries [c][e], e = b*DI*DS + d*DS + n (stride E per chunk)
__global__ __launch_bounds__(256) void k_mid(float* __restrict__ ah,          // aprod in, hin out
                                             const float* __restrict__ rsum) {
    __shared__ float lA[8][32];
    __shared__ float lR[8][32];
    const int tid = threadIdx.x;
    const int s  = tid >> 5;                  // chunk-group 0..7
    const int el = tid & 31;
    const size_t E = (size_t)NBATCH*DI*DS;    // 65536
    const size_t e = (size_t)blockIdx.x*32 + el;

    float a[8], r[8];
    #pragma unroll
    for (int i = 0; i < 8; ++i) {
        size_t idx = (size_t)(s*8 + i)*E + e;
        a[i] = ah[idx];
        r[i] = rsum[idx];
    }
    float A = 1.f, R = 0.f;
    #pragma unroll
    for (int i = 0; i < 8; ++i) {             // compose own 8 chunks
        A = a[i]*A;
        R = fmaf(a[i], R, r[i]);
    }
    lA[s][el] = A; lR[s][el] = R;
    __syncthreads();
    float h = 0.f;                            // prefix of groups < s (h0 = 0)
    for (int k = 0; k < s; ++k)
        h = fmaf(lA[k][el], h, lR[k][el]);
    #pragma unroll
    for (int i = 0; i < 8; ++i) {             // re-walk, write chunk-entry states
        size_t idx = (size_t)(s*8 + i)*E + e;
        ah[idx] = h;
        h = fmaf(a[i], h, r[i]);
    }
}

// ---------------- scan pass 2: LDS-staged (packed), butterfly-reduce y ----------------
__global__ __launch_bounds__(256) void k_scan2(const unsigned short* __restrict__ deltab,
                                               const float* __restrict__ x,
                                               const float* __restrict__ Bm,
                                               const float* __restrict__ Cm,
                                               const float* __restrict__ A_log,
                                               const float* __restrict__ Dv,
                                               const float* __restrict__ hin,
                                               float* __restrict__ y) {
    __shared__ unsigned lxd[LC][64];
    __shared__ float lB[LC][DS];
    __shared__ float lC[LC][DS];
    const int tid = threadIdx.x;
    const int bb = blockIdx.x & 31;
    const int b  = (blockIdx.x >> 5) & 1;
    const int c  = blockIdx.x >> 6;
    const int d0 = bb*64;
    const int lbase = c*LC;

    // ---- coalesced staging ----
    {
        const unsigned short* dsrc = deltab + ((size_t)(b*SEQ + lbase))*DI + d0;
        const float*          xsrc = x      + ((size_t)(b*SEQ + lbase))*DI + d0;
        const int row = tid >> 4, col = (tid & 15)*4;
        #pragma unroll
        for (int i = 0; i < 2; i++) {
            s16x4  dv = *(const s16x4*) (dsrc + (size_t)(row + 16*i)*DI + col);
            float4 xv = *(const float4*)(xsrc + (size_t)(row + 16*i)*DI + col);
            uint4 o;
            o.x = packdu(dv[0], xv.x);
            o.y = packdu(dv[1], xv.y);
            o.z = packdu(dv[2], xv.z);
            o.w = packdu(dv[3], xv.w);
            *(uint4*)&lxd[row + 16*i][col] = o;
        }
        if (tid < 128) {
            const float* bsrc = Bm + ((size_t)(b*SEQ + lbase))*DS;
            const float* csrc = Cm + ((size_t)(b*SEQ + lbase))*DS;
            *(float4*)&lB[tid >> 2][(tid & 3)*4] = *(const float4*)(bsrc + tid*4);
            *(float4*)&lC[tid >> 2][(tid & 3)*4] = *(const float4*)(csrc + tid*4);
        }
    }

    const int lane = tid & 63, widx = tid >> 6;
    const int dlow = lane & 15, q = lane >> 4;
    const int dcol = widx*16 + dlow;
    const int d = d0 + dcol;
    const int n0 = 4*q;

    float4 Alg = *(const float4*)(A_log + (size_t)d*DS + n0);
    float An2[4] = { -__expf(Alg.x)*L2E, -__expf(Alg.y)*L2E,
                     -__expf(Alg.z)*L2E, -__expf(Alg.w)*L2E };
    size_t base = (((size_t)c*NBATCH + b)*DI + d)*DS + n0;
    float4 hv = *(const float4*)(hin + base);
    float h[4] = {hv.x, hv.y, hv.z, hv.w};
    const float Dd = Dv[d];
    float* yp = y + ((size_t)(b*SEQ + lbase))*DI + d;

    __syncthreads();

    #pragma unroll 8
    for (int tt = 0; tt < LC; ++tt) {
        unsigned v = lxd[tt][dcol];
        float dlt = __builtin_bit_cast(float, v << 16);
        float u   = __builtin_bit_cast(float, v & 0xffff0000u);
        float du  = dlt * u;
        float4 bv = *(const float4*)&lB[tt][n0];
        float4 cv = *(const float4*)&lC[tt][n0];
        float bbv[4] = {bv.x, bv.y, bv.z, bv.w};
        float ccv[4] = {cv.x, cv.y, cv.z, cv.w};
        float acc = 0.f;
        #pragma unroll
        for (int j = 0; j < 4; ++j) {
            float da = exp2f(An2[j] * dlt);
            h[j] = fmaf(da, h[j], du * bbv[j]);
            acc  = fmaf(h[j], ccv[j], acc);
        }
        acc += __shfl_xor(acc, 16);
        acc += __shfl_xor(acc, 32);
        if (q == 0) yp[(size_t)tt*DI] = fmaf(u, Dd, acc);
    }
}

extern "C" void kernel_launch(void* const* d_in, const int* in_sizes, int n_in,
                              void* d_out, int out_size, void* d_ws, size_t ws_size,
                              hipStream_t stream) {
    const float* x     = (const float*)d_in[0];
    const float* A_log = (const float*)d_in[1];
    const float* Dv    = (const float*)d_in[2];
    const float* xpw   = (const float*)d_in[3];
    const float* dtw   = (const float*)d_in[4];
    const float* dtb   = (const float*)d_in[5];
    float* out = (float*)d_out;

    const size_t SCN = (size_t)NC*NBATCH*DS*DI;          // 4,194,304 floats

    float* ws    = (float*)d_ws;
    unsigned short* deltab = (unsigned short*)ws;        // ROWS*DI shorts
    float* aprod = ws + ((size_t)ROWS*DI/2);             // SCN floats (hin aliases after k_mid)
    float* rsum  = aprod + SCN;                          // SCN floats
    float* Bm    = rsum + SCN;                           // ROWS*DS
    float* Cm    = Bm + (size_t)ROWS*DS;                 // ROWS*DS
    short* dRb   = (short*)(Cm + (size_t)ROWS*DS);       // ROWS*DTR shorts
    short* wb    = dRb + (size_t)ROWS*DTR;               // 160*2048 shorts
    short* dtwb  = wb  + (size_t)160*2048;               // 2048*128 shorts

    k_castw<<<576, 256, 0, stream>>>(xpw, dtw, wb, dtwb);
    k_gemm1<<<256, 512, 0, stream>>>(x, wb, dRb, Bm, Cm);
    k_gemm2<<<2048, 256, 0, stream>>>(dRb, dtwb, dtb, deltab);
    k_scan1<<<4096, 256, 0, stream>>>(deltab, x, Bm, A_log, aprod, rsum);
    k_mid<<<2048, 256, 0, stream>>>(aprod, rsum);
    k_scan2<<<4096, 256, 0, stream>>>(deltab, x, Bm, Cm, A_log, Dv, aprod, out);
}

// Round 10
// 208.706 us; speedup vs baseline: 1.1221x; 1.1034x over previous
//
#include <hip/hip_runtime.h>
#include <hip/hip_bf16.h>
#include <math.h>

#define DI   2048      // D_INNER
#define DS   16        // D_STATE
#define DTR  128       // DT_RANK
#define NBATCH 2
#define SEQ  2048
#define ROWS (NBATCH*SEQ)   // 4096
#define NE   (DTR + 2*DS)   // 160
#define NC   32             // chunks along L
#define LC   (SEQ/NC)       // 64

typedef float f32x4 __attribute__((ext_vector_type(4)));
typedef short s16x8 __attribute__((ext_vector_type(8)));
typedef short s16x4 __attribute__((ext_vector_type(4)));

#define L2E 1.4426950408889634f

// native exp2: 1 v_exp_f32. Fallback converts back to exp-domain (still native v_exp).
#if __has_builtin(__builtin_amdgcn_exp2f)
#define EXP2(v) __builtin_amdgcn_exp2f(v)
#else
#define EXP2(v) __expf((v)*0.6931471805599453f)
#endif

__device__ inline short f2bf(float f) {
    unsigned u = __builtin_bit_cast(unsigned, f);
    u += 0x7FFFu + ((u >> 16) & 1u);   // RNE
    return (short)(u >> 16);
}

// pack 2 floats -> 2 bf16 (RNE) in one u32 (lowers to v_cvt_pk_bf16_f32)
__device__ inline unsigned pk2(float lo, float hi) {
    union { __hip_bfloat162 h; unsigned u; } cv;
    cv.h = __float22bfloat162_rn(float2{lo, hi});
    return cv.u;
}
// pack (delta_bf16 low | x_bf16 high)
__device__ inline unsigned packdu(short dbf, float xf) {
    return ((unsigned)(unsigned short)f2bf(xf) << 16) | (unsigned)(unsigned short)dbf;
}

// ---------------- cast weights to bf16 ----------------
__global__ __launch_bounds__(256) void k_castw(const float* __restrict__ w,
                                               const float* __restrict__ dtw,
                                               short* __restrict__ wb,
                                               short* __restrict__ dtwb) {
    int i = blockIdx.x*256 + threadIdx.x;     // 4 elems each
    if (i < 81920) {                          // 160*2048/4
        float4 v = ((const float4*)w)[i];
        s16x4 o = { f2bf(v.x), f2bf(v.y), f2bf(v.z), f2bf(v.w) };
        *(s16x4*)(wb + 4*i) = o;
    } else if (i < 147456) {                  // + 2048*128/4
        int j = i - 81920;
        float4 v = ((const float4*)dtw)[j];
        s16x4 o = { f2bf(v.x), f2bf(v.y), f2bf(v.z), f2bf(v.w) };
        *(s16x4*)(dtwb + 4*j) = o;
    }
}

// ---------------- GEMM1: in-block K-split x4, LDS reduce, write dR/B/C directly ----------------
__global__ __launch_bounds__(512) void k_gemm1(const float* __restrict__ x,
                                               const short* __restrict__ wb,
                                               short* __restrict__ dRb,
                                               float* __restrict__ Bm,
                                               float* __restrict__ Cm) {
    __shared__ float lred[2][3][5][64][4];    // 30 KB
    const int tid  = threadIdx.x;
    const int w    = tid >> 6;                // 0..7
    const int lane = tid & 63;
    const int half = w & 1, kq = w >> 1;      // kq 0..3
    const int m16  = blockIdx.x;              // 0..255
    const int r = lane & 15, g = lane >> 4;

    f32x4 acc[5] = {};
    const float* xp    = x  + (size_t)(m16*16 + r)*DI + g*8 + kq*512;
    const short* wbase = wb + (size_t)(half*80 + r)*DI + g*8 + kq*512;
    #pragma unroll 4
    for (int kk = 0; kk < 16; ++kk) {
        const int k0 = kk*32;
        float4 xa = *(const float4*)(xp + k0);
        float4 xc = *(const float4*)(xp + k0 + 4);
        union { s16x8 v; unsigned u[4]; } af;
        af.u[0] = pk2(xa.x, xa.y);
        af.u[1] = pk2(xa.z, xa.w);
        af.u[2] = pk2(xc.x, xc.y);
        af.u[3] = pk2(xc.z, xc.w);
        #pragma unroll
        for (int nf = 0; nf < 5; ++nf) {
            s16x8 bfrag = *(const s16x8*)(wbase + (size_t)nf*16*DI + k0);
            acc[nf] = __builtin_amdgcn_mfma_f32_16x16x32_bf16(af.v, bfrag, acc[nf], 0, 0, 0);
        }
    }
    if (kq > 0) {
        #pragma unroll
        for (int nf = 0; nf < 5; ++nf)
            *(f32x4*)&lred[half][kq-1][nf][lane][0] = acc[nf];
    }
    __syncthreads();
    if (kq == 0) {
        #pragma unroll
        for (int nf = 0; nf < 5; ++nf)
            #pragma unroll
            for (int p = 0; p < 3; ++p)
                acc[nf] += *(const f32x4*)&lred[half][p][nf][lane][0];
        const int orow = m16*16 + g*4;
        #pragma unroll
        for (int nf = 0; nf < 5; ++nf) {
            const int gnf = half*5 + nf;
            const int col = gnf*16 + r;
            #pragma unroll
            for (int j = 0; j < 4; ++j) {
                const int row = orow + j;
                float v = acc[nf][j];
                if (gnf < 8)       dRb[(size_t)row*DTR + col]        = f2bf(v);
                else if (gnf == 8) Bm [(size_t)row*DS + (col - 128)] = v;
                else               Cm [(size_t)row*DS + (col - 144)] = v;
            }
        }
    }
}

// ---------------- GEMM2: delta(bf16) = softplus(dRb @ dtwb^T + bias) — no LDS ----------------
__global__ __launch_bounds__(256) void k_gemm2(const short* __restrict__ dRb,
                                               const short* __restrict__ dtwb,
                                               const float* __restrict__ bias,
                                               unsigned short* __restrict__ deltab) {
    const int wave = blockIdx.x*4 + (threadIdx.x >> 6);
    const int lane = threadIdx.x & 63;
    const int m16 = wave >> 5, nt = wave & 31;
    const int r = lane & 15, g = lane >> 4;

    s16x8 a[4];
    const short* ap = dRb + (size_t)(m16*16 + r)*DTR + g*8;
    #pragma unroll
    for (int ks = 0; ks < 4; ++ks) a[ks] = *(const s16x8*)(ap + ks*32);

    f32x4 acc[4] = {};
    #pragma unroll
    for (int nf = 0; nf < 4; ++nf) {
        const short* bp = dtwb + (size_t)(nt*64 + nf*16 + r)*DTR + g*8;
        #pragma unroll
        for (int ks = 0; ks < 4; ++ks) {
            s16x8 b = *(const s16x8*)(bp + ks*32);
            acc[nf] = __builtin_amdgcn_mfma_f32_16x16x32_bf16(a[ks], b, acc[nf], 0, 0, 0);
        }
    }
    const int orow = m16*16 + g*4;
    #pragma unroll
    for (int nf = 0; nf < 4; ++nf) {
        const int col = nt*64 + nf*16 + r;
        const float bb = bias[col];
        #pragma unroll
        for (int j = 0; j < 4; ++j) {
            float v = acc[nf][j] + bb;
            float sp = fmaxf(v, 0.f) + __logf(1.f + __expf(-fabsf(v)));
            deltab[(size_t)(orow + j)*DI + col] = (unsigned short)f2bf(sp);
        }
    }
}

// ---------------- scan pass 1: LC=64 staged, 2 d-cols/thread, native exp2 ----------------
// block = 256 thr, stages 128 d-cols. grid = 32c x 2b x 16 dblk = 1024
__global__ __launch_bounds__(256) void k_scan1(const unsigned short* __restrict__ deltab,
                                               const float* __restrict__ x,
                                               const float* __restrict__ Bm,
                                               const float* __restrict__ A_log,
                                               float* __restrict__ aprod,
                                               float* __restrict__ rsum) {
    __shared__ unsigned lxd[LC][128];   // 32 KB
    __shared__ float lB[LC][DS];        // 4 KB
    const int tid = threadIdx.x;
    const int bb = blockIdx.x & 15;          // d-block of 128
    const int b  = (blockIdx.x >> 4) & 1;
    const int c  = blockIdx.x >> 5;          // 0..31
    const int d0 = bb*128;
    const int lbase = c*LC;

    // ---- coalesced staging ----
    {
        const unsigned short* dsrc = deltab + ((size_t)(b*SEQ + lbase))*DI + d0;
        const float*          xsrc = x      + ((size_t)(b*SEQ + lbase))*DI + d0;
        const int srow = tid >> 5, scol = (tid & 31)*4;
        #pragma unroll
        for (int i = 0; i < 8; i++) {
            int rr = srow + 8*i;
            s16x4  dv = *(const s16x4*) (dsrc + (size_t)rr*DI + scol);
            float4 xv = *(const float4*)(xsrc + (size_t)rr*DI + scol);
            uint4 o;
            o.x = packdu(dv[0], xv.x);
            o.y = packdu(dv[1], xv.y);
            o.z = packdu(dv[2], xv.z);
            o.w = packdu(dv[3], xv.w);
            *(uint4*)&lxd[rr][scol] = o;
        }
        const float* bsrc = Bm + ((size_t)(b*SEQ + lbase))*DS;
        *(float4*)&lB[tid >> 2][(tid & 3)*4] = *(const float4*)(bsrc + tid*4);
    }

    const int lane = tid & 63, widx = tid >> 6;
    const int dlow = lane & 15, q = lane >> 4;
    const int ca = widx*32 + dlow, cb = ca + 16;     // two LDS d-cols
    const int dA = d0 + ca, dB = d0 + cb;
    const int n0 = 4*q;

    float4 AlgA = *(const float4*)(A_log + (size_t)dA*DS + n0);
    float4 AlgB = *(const float4*)(A_log + (size_t)dB*DS + n0);
    float An2[8] = { -__expf(AlgA.x)*L2E, -__expf(AlgA.y)*L2E,
                     -__expf(AlgA.z)*L2E, -__expf(AlgA.w)*L2E,
                     -__expf(AlgB.x)*L2E, -__expf(AlgB.y)*L2E,
                     -__expf(AlgB.z)*L2E, -__expf(AlgB.w)*L2E };
    float r0[4] = {0.f,0.f,0.f,0.f}, r1[4] = {0.f,0.f,0.f,0.f};
    float S0 = 0.f, S1 = 0.f;

    __syncthreads();

    #pragma unroll 4
    for (int tt = 0; tt < LC; ++tt) {
        unsigned va = lxd[tt][ca];
        unsigned vb = lxd[tt][cb];
        float dltA = __builtin_bit_cast(float, va << 16);
        float uA   = __builtin_bit_cast(float, va & 0xffff0000u);
        float dltB = __builtin_bit_cast(float, vb << 16);
        float uB   = __builtin_bit_cast(float, vb & 0xffff0000u);
        float duA = dltA * uA, duB = dltB * uB;
        S0 += dltA; S1 += dltB;
        float4 bv = *(const float4*)&lB[tt][n0];
        float bbv[4] = {bv.x, bv.y, bv.z, bv.w};
        #pragma unroll
        for (int j = 0; j < 4; ++j) {
            r0[j] = fmaf(EXP2(An2[j]   * dltA), r0[j], duA * bbv[j]);
            r1[j] = fmaf(EXP2(An2[j+4] * dltB), r1[j], duB * bbv[j]);
        }
    }
    size_t baseA = (((size_t)c*NBATCH + b)*DI + dA)*DS + n0;
    size_t baseB = (((size_t)c*NBATCH + b)*DI + dB)*DS + n0;
    *(f32x4*)(aprod + baseA) = (f32x4){ EXP2(An2[0]*S0), EXP2(An2[1]*S0),
                                        EXP2(An2[2]*S0), EXP2(An2[3]*S0) };
    *(f32x4*)(aprod + baseB) = (f32x4){ EXP2(An2[4]*S1), EXP2(An2[5]*S1),
                                        EXP2(An2[6]*S1), EXP2(An2[7]*S1) };
    *(f32x4*)(rsum + baseA) = (f32x4){ r0[0], r0[1], r0[2], r0[3] };
    *(f32x4*)(rsum + baseB) = (f32x4){ r1[0], r1[1], r1[2], r1[3] };
}

// ---------------- middle: 2-level combine (8 groups x 4 chunks), hin in-place ----------------
__global__ __launch_bounds__(256) void k_mid(float* __restrict__ ah,          // aprod in, hin out
                                             const float* __restrict__ rsum) {
    __shared__ float lA[8][32];
    __shared__ float lR[8][32];
    const int tid = threadIdx.x;
    const int s  = tid >> 5;                  // chunk-group 0..7
    const int el = tid & 31;
    const size_t E = (size_t)NBATCH*DI*DS;    // 65536
    const size_t e = (size_t)blockIdx.x*32 + el;

    float a[4], r[4];
    #pragma unroll
    for (int i = 0; i < 4; ++i) {
        size_t idx = (size_t)(s*4 + i)*E + e;
        a[i] = ah[idx];
        r[i] = rsum[idx];
    }
    float A = 1.f, R = 0.f;
    #pragma unroll
    for (int i = 0; i < 4; ++i) {             // compose own 4 chunks
        A = a[i]*A;
        R = fmaf(a[i], R, r[i]);
    }
    lA[s][el] = A; lR[s][el] = R;
    __syncthreads();
    float h = 0.f;                            // prefix of groups < s
    for (int k = 0; k < s; ++k)
        h = fmaf(lA[k][el], h, lR[k][el]);
    #pragma unroll
    for (int i = 0; i < 4; ++i) {             // re-walk, write chunk-entry states
        size_t idx = (size_t)(s*4 + i)*E + e;
        ah[idx] = h;
        h = fmaf(a[i], h, r[i]);
    }
}

// ---------------- scan pass 2: LC=64 staged, 2 d-cols/thread, butterfly y ----------------
__global__ __launch_bounds__(256) void k_scan2(const unsigned short* __restrict__ deltab,
                                               const float* __restrict__ x,
                                               const float* __restrict__ Bm,
                                               const float* __restrict__ Cm,
                                               const float* __restrict__ A_log,
                                               const float* __restrict__ Dv,
                                               const float* __restrict__ hin,
                                               float* __restrict__ y) {
    __shared__ unsigned lxd[LC][128];   // 32 KB
    __shared__ float lB[LC][DS];        // 4 KB
    __shared__ float lC[LC][DS];        // 4 KB
    const int tid = threadIdx.x;
    const int bb = blockIdx.x & 15;
    const int b  = (blockIdx.x >> 4) & 1;
    const int c  = blockIdx.x >> 5;
    const int d0 = bb*128;
    const int lbase = c*LC;

    // ---- coalesced staging ----
    {
        const unsigned short* dsrc = deltab + ((size_t)(b*SEQ + lbase))*DI + d0;
        const float*          xsrc = x      + ((size_t)(b*SEQ + lbase))*DI + d0;
        const int srow = tid >> 5, scol = (tid & 31)*4;
        #pragma unroll
        for (int i = 0; i < 8; i++) {
            int rr = srow + 8*i;
            s16x4  dv = *(const s16x4*) (dsrc + (size_t)rr*DI + scol);
            float4 xv = *(const float4*)(xsrc + (size_t)rr*DI + scol);
            uint4 o;
            o.x = packdu(dv[0], xv.x);
            o.y = packdu(dv[1], xv.y);
            o.z = packdu(dv[2], xv.z);
            o.w = packdu(dv[3], xv.w);
            *(uint4*)&lxd[rr][scol] = o;
        }
        const float* bsrc = Bm + ((size_t)(b*SEQ + lbase))*DS;
        const float* csrc = Cm + ((size_t)(b*SEQ + lbase))*DS;
        *(float4*)&lB[tid >> 2][(tid & 3)*4] = *(const float4*)(bsrc + tid*4);
        *(float4*)&lC[tid >> 2][(tid & 3)*4] = *(const float4*)(csrc + tid*4);
    }

    const int lane = tid & 63, widx = tid >> 6;
    const int dlow = lane & 15, q = lane >> 4;
    const int ca = widx*32 + dlow, cb = ca + 16;
    const int dA = d0 + ca, dB = d0 + cb;
    const int n0 = 4*q;

    float4 AlgA = *(const float4*)(A_log + (size_t)dA*DS + n0);
    float4 AlgB = *(const float4*)(A_log + (size_t)dB*DS + n0);
    float An2[8] = { -__expf(AlgA.x)*L2E, -__expf(AlgA.y)*L2E,
                     -__expf(AlgA.z)*L2E, -__expf(AlgA.w)*L2E,
                     -__expf(AlgB.x)*L2E, -__expf(AlgB.y)*L2E,
                     -__expf(AlgB.z)*L2E, -__expf(AlgB.w)*L2E };
    size_t baseA = (((size_t)c*NBATCH + b)*DI + dA)*DS + n0;
    size_t baseB = (((size_t)c*NBATCH + b)*DI + dB)*DS + n0;
    float4 hvA = *(const float4*)(hin + baseA);
    float4 hvB = *(const float4*)(hin + baseB);
    float h0[4] = {hvA.x, hvA.y, hvA.z, hvA.w};
    float h1[4] = {hvB.x, hvB.y, hvB.z, hvB.w};
    const float DdA = Dv[dA], DdB = Dv[dB];
    float* yp = y + ((size_t)(b*SEQ + lbase))*DI + d0;

    __syncthreads();

    #pragma unroll 4
    for (int tt = 0; tt < LC; ++tt) {
        unsigned va = lxd[tt][ca];
        unsigned vb = lxd[tt][cb];
        float dltA = __builtin_bit_cast(float, va << 16);
        float uA   = __builtin_bit_cast(float, va & 0xffff0000u);
        float dltB = __builtin_bit_cast(float, vb << 16);
        float uB   = __builtin_bit_cast(float, vb & 0xffff0000u);
        float duA = dltA * uA, duB = dltB * uB;
        float4 bv = *(const float4*)&lB[tt][n0];
        float4 cv = *(const float4*)&lC[tt][n0];
        float bbv[4] = {bv.x, bv.y, bv.z, bv.w};
        float ccv[4] = {cv.x, cv.y, cv.z, cv.w};
        float accA = 0.f, accB = 0.f;
        #pragma unroll
        for (int j = 0; j < 4; ++j) {
            h0[j] = fmaf(EXP2(An2[j]   * dltA), h0[j], duA * bbv[j]);
            h1[j] = fmaf(EXP2(An2[j+4] * dltB), h1[j], duB * bbv[j]);
            accA  = fmaf(h0[j], ccv[j], accA);
            accB  = fmaf(h1[j], ccv[j], accB);
        }
        accA += __shfl_xor(accA, 16);
        accA += __shfl_xor(accA, 32);
        accB += __shfl_xor(accB, 16);
        accB += __shfl_xor(accB, 32);
        if (q == 0) {
            yp[(size_t)tt*DI + ca] = fmaf(uA, DdA, accA);
            yp[(size_t)tt*DI + cb] = fmaf(uB, DdB, accB);
        }
    }
}

extern "C" void kernel_launch(void* const* d_in, const int* in_sizes, int n_in,
                              void* d_out, int out_size, void* d_ws, size_t ws_size,
                              hipStream_t stream) {
    const float* x     = (const float*)d_in[0];
    const float* A_log = (const float*)d_in[1];
    const float* Dv    = (const float*)d_in[2];
    const float* xpw   = (const float*)d_in[3];
    const float* dtw   = (const float*)d_in[4];
    const float* dtb   = (const float*)d_in[5];
    float* out = (float*)d_out;

    const size_t SCN = (size_t)NC*NBATCH*DS*DI;          // 2,097,152 floats

    float* ws    = (float*)d_ws;
    unsigned short* deltab = (unsigned short*)ws;        // ROWS*DI shorts
    float* aprod = ws + ((size_t)ROWS*DI/2);             // SCN floats (hin aliases after k_mid)
    float* rsum  = aprod + SCN;                          // SCN floats
    float* Bm    = rsum + SCN;                           // ROWS*DS
    float* Cm    = Bm + (size_t)ROWS*DS;                 // ROWS*DS
    short* dRb   = (short*)(Cm + (size_t)ROWS*DS);       // ROWS*DTR shorts
    short* wb    = dRb + (size_t)ROWS*DTR;               // 160*2048 shorts
    short* dtwb  = wb  + (size_t)160*2048;               // 2048*128 shorts

    k_castw<<<576, 256, 0, stream>>>(xpw, dtw, wb, dtwb);
    k_gemm1<<<256, 512, 0, stream>>>(x, wb, dRb, Bm, Cm);
    k_gemm2<<<2048, 256, 0, stream>>>(dRb, dtwb, dtb, deltab);
    k_scan1<<<1024, 256, 0, stream>>>(deltab, x, Bm, A_log, aprod, rsum);
    k_mid<<<2048, 256, 0, stream>>>(aprod, rsum);
    k_scan2<<<1024, 256, 0, stream>>>(deltab, x, Bm, Cm, A_log, Dv, aprod, out);
}